// Round 1
// baseline (758.188 us; speedup 1.0000x reference)
//
#include <hip/hip_runtime.h>

typedef _Float16 f16;
typedef _Float16 f16x4 __attribute__((ext_vector_type(4)));
typedef _Float16 f16x8 __attribute__((ext_vector_type(8)));
typedef float f32x4 __attribute__((ext_vector_type(4)));

#define MFMA_F16(A, B, C) __builtin_amdgcn_mfma_f32_16x16x32_f16(A, B, C, 0, 0, 0)

// x: [32,64,64,384] fp32 -> windows of 8x8 -> 2048 windows x 64 tokens
// heads=12, dim_head=32, INNER=384, qkv cols = 1152
static constexpr int ROWS = 32 * 64 * 64;  // 131072 token rows
static constexpr float SCALE = 0.17677669529663687f;  // 32^-0.5

// workspace layout (bytes)
static constexpr size_t WQKVT_OFF = 0;                              // f16 [1152][384] (B^T)
static constexpr size_t WOUTT_OFF = (size_t)1152 * 384 * 2;         // f16 [384][384]  (B^T)
static constexpr size_t QKV_OFF   = WOUTT_OFF + (size_t)384 * 384 * 2;  // f16 [131072][1152]
static constexpr size_t WS_NEEDED = QKV_OFF + (size_t)ROWS * 1152 * 2;  // ~303 MB

// ---------------- weight prep: transpose + fp32->fp16 ----------------
__global__ __launch_bounds__(256) void k_prep(const float* __restrict__ wqkv,
                                              const float* __restrict__ wout,
                                              f16* __restrict__ wqkvT,
                                              f16* __restrict__ woutT) {
  int idx = blockIdx.x * 256 + threadIdx.x;
  if (idx < 1152 * 384) {
    int c = idx / 384, k = idx - c * 384;
    wqkvT[idx] = (f16)wqkv[k * 1152 + c];
  } else {
    int i = idx - 1152 * 384;
    if (i < 384 * 384) {
      int c = i / 384, k = i - c * 384;
      woutT[i] = (f16)wout[k * 384 + c];
    }
  }
}

// ---------------- QKV GEMM: [131072,384](fp32) @ [384,1152] -> fp16 ----------------
// 128x128 tile, BK=64, 4 waves in 2x2, 16x16x32 fp16 MFMA.
__global__ __launch_bounds__(256) void k_qkv(const float* __restrict__ X,
                                             const f16* __restrict__ Wt,
                                             f16* __restrict__ qkv) {
  __shared__ f16 smem[2 * 128 * 72];  // 36,864 B
  f16* As = smem;            // [128][64+8pad]
  f16* Bs = smem + 128 * 72; // [128][64+8pad]  (rows = output cols, B^T)

  const int tid = threadIdx.x;
  // XCD swizzle: id%8 = XCD (dispatch round-robin). Per XCD, 9 consecutive
  // blocks share one m-tile so the A-tile is fetched into that XCD's L2 once.
  const int id = blockIdx.x;          // 0..9215
  const int s = id & 7, t = id >> 3;  // t in [0,1152)
  const int n0 = (t % 9) * 128;
  const int m0 = (s * 128 + t / 9) * 128;

  const int lane = tid & 63, wave = tid >> 6;
  const int lane15 = lane & 15, quad = lane >> 4;
  const int wm = (wave >> 1) * 64, wn = (wave & 1) * 64;

  f32x4 acc[4][4] = {};
  for (int ks = 0; ks < 384; ks += 64) {
    // stage A: fp32 load, convert to fp16
#pragma unroll
    for (int l = 0; l < 8; ++l) {
      int idx = l * 256 + tid;
      int row = idx >> 4, c4 = (idx & 15) * 4;
      float4 xv = *(const float4*)&X[(size_t)(m0 + row) * 384 + ks + c4];
      f16x4 hv;
      hv[0] = (f16)xv.x; hv[1] = (f16)xv.y; hv[2] = (f16)xv.z; hv[3] = (f16)xv.w;
      *(f16x4*)&As[row * 72 + c4] = hv;
    }
    // stage B^T (already fp16)
#pragma unroll
    for (int l = 0; l < 4; ++l) {
      int idx = l * 256 + tid;
      int nr = idx >> 3, c8 = (idx & 7) * 8;
      *(f16x8*)&Bs[nr * 72 + c8] = *(const f16x8*)&Wt[(size_t)(n0 + nr) * 384 + ks + c8];
    }
    __syncthreads();
#pragma unroll
    for (int kk = 0; kk < 64; kk += 32) {
      f16x8 af[4], bf[4];
#pragma unroll
      for (int i = 0; i < 4; ++i)
        af[i] = *(const f16x8*)&As[(wm + i * 16 + lane15) * 72 + kk + quad * 8];
#pragma unroll
      for (int j = 0; j < 4; ++j)
        bf[j] = *(const f16x8*)&Bs[(wn + j * 16 + lane15) * 72 + kk + quad * 8];
#pragma unroll
      for (int i = 0; i < 4; ++i)
#pragma unroll
        for (int j = 0; j < 4; ++j)
          acc[i][j] = MFMA_F16(af[i], bf[j], acc[i][j]);
    }
    __syncthreads();
  }
  // epilogue: fp32 acc -> fp16, bounce through LDS for coalesced 16B stores
  f16* Cs = smem;  // [128][128+8pad] = 34,816 B, fits in smem
#pragma unroll
  for (int i = 0; i < 4; ++i)
#pragma unroll
    for (int j = 0; j < 4; ++j)
#pragma unroll
      for (int v = 0; v < 4; ++v)
        Cs[(wm + i * 16 + quad * 4 + v) * 136 + wn + j * 16 + lane15] = (f16)acc[i][j][v];
  __syncthreads();
#pragma unroll
  for (int l = 0; l < 8; ++l) {
    int idx = l * 256 + tid;
    int row = idx >> 4, c8 = (idx & 15) * 8;
    *(f16x8*)&qkv[(size_t)(m0 + row) * 1152 + n0 + c8] = *(const f16x8*)&Cs[row * 136 + c8];
  }
}

// ---------------- attention per window + fused out-projection ----------------
// block = 256 thr (4 waves), one block per window. wave w owns score rows w*16..w*16+15.
__global__ __launch_bounds__(256) void k_attn(const f16* __restrict__ qkv,
                                              const f16* __restrict__ woutT,
                                              const float* __restrict__ b_out,
                                              float* __restrict__ out) {
  __shared__ f16 vt[32 * 72];     // v^T for current head: [dim][64 tok + 8 pad]
  __shared__ f16 Pw[4][16 * 72];  // per-wave P tile [16][64+8]
  __shared__ f16 ao[64 * 392];    // attention output [64][384+8]
  // total LDS = 64,000 B -> 2 blocks/CU

  const int tid = threadIdx.x;
  const int lane = tid & 63, wave = tid >> 6;
  const int lane15 = lane & 15, quad = lane >> 4;

  const int blk = blockIdx.x;  // 0..2047
  const int b = blk >> 6, rem = blk & 63, wh = rem >> 3, ww = rem & 7;
  const int base = b * 4096 + wh * 512 + ww * 8;  // natural row of token (0,0)

  // per-lane source rows (token t -> natural row base + (t>>3)*64 + (t&7))
  const int tq = wave * 16 + lane15;
  const size_t rowq = (size_t)(base + (tq >> 3) * 64 + (tq & 7)) * 1152;
  size_t rowk[4];
#pragma unroll
  for (int tj = 0; tj < 4; ++tj) {
    int tk = tj * 16 + lane15;
    rowk[tj] = (size_t)(base + (tk >> 3) * 64 + (tk & 7)) * 1152;
  }
  const int vt_t = tid >> 2, vt_d8 = (tid & 3) * 8;
  const size_t rowv = (size_t)(base + (vt_t >> 3) * 64 + (vt_t & 7)) * 1152;

#pragma unroll 1
  for (int h = 0; h < 12; ++h) {
    const int hoff = h * 32;
    // stage V transposed: vt[d][t]
    f16x8 vv = *(const f16x8*)&qkv[rowv + 768 + hoff + vt_d8];
#pragma unroll
    for (int j = 0; j < 8; ++j) vt[(vt_d8 + j) * 72 + vt_t] = vv[j];
    __syncthreads();

    // QK^T: q A-frag and k B-frags straight from global (16B/lane)
    f16x8 aq = *(const f16x8*)&qkv[rowq + hoff + quad * 8];
    f32x4 sim[4];
#pragma unroll
    for (int tj = 0; tj < 4; ++tj) {
      f16x8 bk = *(const f16x8*)&qkv[rowk[tj] + 384 + hoff + quad * 8];
      f32x4 z = {};
      sim[tj] = MFMA_F16(aq, bk, z);
    }
#pragma unroll
    for (int tj = 0; tj < 4; ++tj)
#pragma unroll
      for (int v = 0; v < 4; ++v) sim[tj][v] *= SCALE;

    // exact softmax; row r=quad*4+v lives in the quad's 16 lanes x 4 tj
    float pv[4][4];
#pragma unroll
    for (int v = 0; v < 4; ++v) {
      float m = fmaxf(fmaxf(sim[0][v], sim[1][v]), fmaxf(sim[2][v], sim[3][v]));
#pragma unroll
      for (int off = 1; off < 16; off <<= 1) m = fmaxf(m, __shfl_xor(m, off));
      float ssum = 0.f;
#pragma unroll
      for (int tj = 0; tj < 4; ++tj) {
        pv[tj][v] = __expf(sim[tj][v] - m);
        ssum += pv[tj][v];
      }
#pragma unroll
      for (int off = 1; off < 16; off <<= 1) ssum += __shfl_xor(ssum, off);
      float inv = 1.0f / ssum;
#pragma unroll
      for (int tj = 0; tj < 4; ++tj) pv[tj][v] *= inv;
    }
    // P -> LDS (C-layout -> A-frag layout round trip)
#pragma unroll
    for (int tj = 0; tj < 4; ++tj)
#pragma unroll
      for (int v = 0; v < 4; ++v)
        Pw[wave][(quad * 4 + v) * 72 + tj * 16 + lane15] = (f16)pv[tj][v];
    __syncthreads();  // conservative: P write -> read ordering

    // PV: [16x64] @ [64x32]
    f32x4 o[2] = {};
#pragma unroll
    for (int kk = 0; kk < 64; kk += 32) {
      f16x8 pa = *(const f16x8*)&Pw[wave][lane15 * 72 + kk + quad * 8];
#pragma unroll
      for (int tj = 0; tj < 2; ++tj) {
        f16x8 bvv = *(const f16x8*)&vt[(tj * 16 + lane15) * 72 + kk + quad * 8];
        o[tj] = MFMA_F16(pa, bvv, o[tj]);
      }
    }
#pragma unroll
    for (int tj = 0; tj < 2; ++tj)
#pragma unroll
      for (int v = 0; v < 4; ++v)
        ao[(wave * 16 + quad * 4 + v) * 392 + hoff + tj * 16 + lane15] = (f16)o[tj][v];
    __syncthreads();
  }

  // fused out-projection: [64,384] @ w_out + bias; wave covers 96 output cols
  const int n0 = wave * 96;
  float biasv[6];
#pragma unroll
  for (int tj = 0; tj < 6; ++tj) biasv[tj] = b_out[n0 + tj * 16 + lane15];
  f32x4 acc[4][6] = {};
  for (int ksi = 0; ksi < 12; ++ksi) {
    const int ks = ksi * 32;
    f16x8 af[4];
#pragma unroll
    for (int ti = 0; ti < 4; ++ti)
      af[ti] = *(const f16x8*)&ao[(ti * 16 + lane15) * 392 + ks + quad * 8];
#pragma unroll
    for (int tj = 0; tj < 6; ++tj) {
      f16x8 bf = *(const f16x8*)&woutT[(size_t)(n0 + tj * 16 + lane15) * 384 + ks + quad * 8];
#pragma unroll
      for (int ti = 0; ti < 4; ++ti) acc[ti][tj] = MFMA_F16(af[ti], bf, acc[ti][tj]);
    }
  }
#pragma unroll
  for (int ti = 0; ti < 4; ++ti)
#pragma unroll
    for (int v = 0; v < 4; ++v) {
      int t = ti * 16 + quad * 4 + v;
      size_t row = (size_t)(base + (t >> 3) * 64 + (t & 7)) * 384;
#pragma unroll
      for (int tj = 0; tj < 6; ++tj)
        out[row + n0 + tj * 16 + lane15] = acc[ti][tj][v] + biasv[tj];
    }
}

extern "C" void kernel_launch(void* const* d_in, const int* in_sizes, int n_in,
                              void* d_out, int out_size, void* d_ws, size_t ws_size,
                              hipStream_t stream) {
  const float* x = (const float*)d_in[0];
  const float* w_qkv = (const float*)d_in[1];
  const float* w_out = (const float*)d_in[2];
  const float* b_out = (const float*)d_in[3];
  float* out = (float*)d_out;

  if (ws_size < WS_NEEDED) return;  // deterministic guard: poison-level absmax => ws too small

  char* ws = (char*)d_ws;
  f16* wqkvT = (f16*)(ws + WQKVT_OFF);
  f16* woutT = (f16*)(ws + WOUTT_OFF);
  f16* qkv = (f16*)(ws + QKV_OFF);

  hipLaunchKernelGGL(k_prep, dim3(2304), dim3(256), 0, stream, w_qkv, w_out, wqkvT, woutT);
  hipLaunchKernelGGL(k_qkv, dim3(9216), dim3(256), 0, stream, x, wqkvT, qkv);
  hipLaunchKernelGGL(k_attn, dim3(2048), dim3(256), 0, stream, qkv, woutT, b_out, out);
}